// Round 1
// baseline (738.225 us; speedup 1.0000x reference)
//
#include <hip/hip_runtime.h>
#include <hip/hip_bf16.h>

#define E_ 160
#define CAP_ 120
#define S_ 3200
#define H_ 2048
#define I_ 192
#define K_ 6
#define MP_ 128   // padded rows per expert (CAP=120 -> 128)

typedef __attribute__((ext_vector_type(8))) short short8;
typedef __attribute__((ext_vector_type(4))) float f32x4;

// pack two fp32 -> two bf16 (truncate/RTZ) in one v_perm_b32
__device__ __forceinline__ unsigned pack2bf(float a, float b) {
  return __builtin_amdgcn_perm(__float_as_uint(b), __float_as_uint(a), 0x07060302u);
}
__device__ __forceinline__ short f2bf1(float a) {
  return (short)(__float_as_uint(a) >> 16);
}
__device__ __forceinline__ float bf2f(short s) {
  return __uint_as_float(((unsigned)(unsigned short)s) << 16);
}

// ---------------- kernel 1: gather + cast to bf16, pad rows zeroed ----------
// grid: E*128 blocks, 256 thr. Block b = e*128 + c; thread covers 8 cols.
__global__ __launch_bounds__(256) void k_gather(
    const float* __restrict__ hidden, const int* __restrict__ tok,
    short* __restrict__ xb)
{
  int b = blockIdx.x;
  int e = b >> 7, c = b & 127;
  int col = threadIdx.x * 8;
  short* dst = xb + (size_t)b * H_ + col;
  if (c < CAP_) {
    int row = tok[e * CAP_ + c];
    const float* src = hidden + (size_t)row * H_ + col;
    float4 f0 = *(const float4*)src;
    float4 f1 = *(const float4*)(src + 4);
    int4 v;
    v.x = (int)pack2bf(f0.x, f0.y); v.y = (int)pack2bf(f0.z, f0.w);
    v.z = (int)pack2bf(f1.x, f1.y); v.w = (int)pack2bf(f1.z, f1.w);
    *(int4*)dst = v;
  } else {
    *(int4*)dst = make_int4(0, 0, 0, 0);
  }
}

// ---------------- kernel 2: gate+up GEMM + silu, h -> bf16 ------------------
// grid: E*3 blocks (expert e, i-tile of 64). C tile 128x128: cols 0-63 gate,
// cols 64-127 up. 4 waves in 2x2; wave tile 64x64. BK=64, 32 K-iters.
__global__ __launch_bounds__(256) void k_gateup(
    const short* __restrict__ xb, const float* __restrict__ gw,
    const float* __restrict__ uw, short* __restrict__ hb)
{
  __shared__ __align__(16) char smem[34816];
  short* As = (short*)smem;        // [128][64] bf16
  short* Bs = As + 128 * 64;       // [128][64] bf16

  int bid = blockIdx.x;
  int e = bid / 3, t = bid - e * 3;
  int i0 = t * 64;
  int tid = threadIdx.x;
  int lane = tid & 63, w = tid >> 6;
  int wr = w >> 1, wc = w & 1;
  int lrow = lane & 15, lq = lane >> 4;

  f32x4 acc[4][4] = {};
  const size_t xbase = (size_t)e * MP_ * H_;

  for (int kk = 0; kk < H_ / 64; ++kk) {
    int k0 = kk * 64;
    // stage A (already bf16): 128x64 = 16KB
#pragma unroll
    for (int r = 0; r < 4; ++r) {
      int q = r * 256 + tid;
      int row = q >> 3, cc = q & 7;
      int4 v = *(const int4*)(xb + xbase + (size_t)row * H_ + k0 + cc * 8);
      *(int4*)(As + row * 64 + cc * 8) = v;
    }
    // stage B (fp32 -> bf16): rows 0-63 gate, 64-127 up
#pragma unroll
    for (int r = 0; r < 8; ++r) {
      int p = r * 256 + tid;
      int row = p >> 4, cc = p & 15;
      const float* srcw = (row < 64)
          ? (gw + ((size_t)e * I_ + i0 + row) * H_ + k0 + cc * 4)
          : (uw + ((size_t)e * I_ + i0 + row - 64) * H_ + k0 + cc * 4);
      float4 f = *(const float4*)srcw;
      uint2 pv;
      pv.x = pack2bf(f.x, f.y); pv.y = pack2bf(f.z, f.w);
      *(uint2*)(Bs + row * 64 + cc * 4) = pv;
    }
    __syncthreads();
#pragma unroll
    for (int ks = 0; ks < 2; ++ks) {
      int koff = ks * 32 + lq * 8;
      short8 a[4], bb[4];
#pragma unroll
      for (int tr = 0; tr < 4; ++tr)
        a[tr] = *(const short8*)(As + (wr * 64 + tr * 16 + lrow) * 64 + koff);
#pragma unroll
      for (int tc = 0; tc < 4; ++tc)
        bb[tc] = *(const short8*)(Bs + (wc * 64 + tc * 16 + lrow) * 64 + koff);
#pragma unroll
      for (int tr = 0; tr < 4; ++tr)
#pragma unroll
        for (int tc = 0; tc < 4; ++tc)
          acc[tr][tc] = __builtin_amdgcn_mfma_f32_16x16x32_bf16(
              a[tr], bb[tc], acc[tr][tc], 0, 0, 0);
    }
    __syncthreads();
  }

  // epilogue: waves wc=0 hold gate (cols 0-63), wc=1 hold up (cols 64-127).
  // Exchange g via LDS [2][64][68] fp32, then h = silu(g)*u.
  float* exch = (float*)smem;
  if (wc == 0) {
#pragma unroll
    for (int tr = 0; tr < 4; ++tr)
#pragma unroll
      for (int tc = 0; tc < 4; ++tc)
#pragma unroll
        for (int rg = 0; rg < 4; ++rg) {
          int lr = tr * 16 + lq * 4 + rg;
          int lcol = tc * 16 + lrow;
          exch[(wr * 64 + lr) * 68 + lcol] = acc[tr][tc][rg];
        }
  }
  __syncthreads();
  if (wc == 1) {
#pragma unroll
    for (int tr = 0; tr < 4; ++tr)
#pragma unroll
      for (int tc = 0; tc < 4; ++tc)
#pragma unroll
        for (int rg = 0; rg < 4; ++rg) {
          int lr = tr * 16 + lq * 4 + rg;
          int lcol = tc * 16 + lrow;
          float g = exch[(wr * 64 + lr) * 68 + lcol];
          float u = acc[tr][tc][rg];
          float hv = g / (1.f + __expf(-g)) * u;
          hb[((size_t)e * MP_ + wr * 64 + lr) * I_ + i0 + lcol] = f2bf1(hv);
        }
  }
}

// ---------------- kernel 3: down GEMM, o -> bf16 compact [E*120][H] ---------
// grid: E*16 (expert e, 128-wide h-tile). BK=64, 3 K-iters (K=192).
__global__ __launch_bounds__(256) void k_down(
    const short* __restrict__ hb, const float* __restrict__ dw,
    short* __restrict__ ob)
{
  __shared__ __align__(16) short As[128 * 64];
  __shared__ __align__(16) short Bs[128 * 64];
  int bid = blockIdx.x;
  int e = bid >> 4, t = bid & 15;
  int n0 = t * 128;
  int tid = threadIdx.x;
  int lane = tid & 63, w = tid >> 6;
  int wr = w >> 1, wc = w & 1;
  int lrow = lane & 15, lq = lane >> 4;

  f32x4 acc[4][4] = {};

  for (int kk = 0; kk < 3; ++kk) {
    int k0 = kk * 64;
#pragma unroll
    for (int r = 0; r < 4; ++r) {
      int q = r * 256 + tid;
      int row = q >> 3, cc = q & 7;
      int4 v = *(const int4*)(hb + ((size_t)e * MP_ + row) * I_ + k0 + cc * 8);
      *(int4*)(As + row * 64 + cc * 8) = v;
    }
#pragma unroll
    for (int r = 0; r < 8; ++r) {
      int p = r * 256 + tid;
      int row = p >> 4, cc = p & 15;
      const float* srcw = dw + ((size_t)e * H_ + n0 + row) * I_ + k0 + cc * 4;
      float4 f = *(const float4*)srcw;
      uint2 pv;
      pv.x = pack2bf(f.x, f.y); pv.y = pack2bf(f.z, f.w);
      *(uint2*)(Bs + row * 64 + cc * 4) = pv;
    }
    __syncthreads();
#pragma unroll
    for (int ks = 0; ks < 2; ++ks) {
      int koff = ks * 32 + lq * 8;
      short8 a[4], bb[4];
#pragma unroll
      for (int tr = 0; tr < 4; ++tr)
        a[tr] = *(const short8*)(As + (wr * 64 + tr * 16 + lrow) * 64 + koff);
#pragma unroll
      for (int tc = 0; tc < 4; ++tc)
        bb[tc] = *(const short8*)(Bs + (wc * 64 + tc * 16 + lrow) * 64 + koff);
#pragma unroll
      for (int tr = 0; tr < 4; ++tr)
#pragma unroll
        for (int tc = 0; tc < 4; ++tc)
          acc[tr][tc] = __builtin_amdgcn_mfma_f32_16x16x32_bf16(
              a[tr], bb[tc], acc[tr][tc], 0, 0, 0);
    }
    __syncthreads();
  }

  // store compact rows c < 120
#pragma unroll
  for (int tr = 0; tr < 4; ++tr) {
#pragma unroll
    for (int rg = 0; rg < 4; ++rg) {
      int c = wr * 64 + tr * 16 + lq * 4 + rg;
      if (c < CAP_) {
#pragma unroll
        for (int tc = 0; tc < 4; ++tc) {
          int col = n0 + wc * 64 + tc * 16 + lrow;
          ob[((size_t)e * CAP_ + c) * H_ + col] = f2bf1(acc[tr][tc][rg]);
        }
      }
    }
  }
}

// ---------------- kernel 4: gather-combine -----------------------------------
// grid: S blocks, 256 thr; thread covers 8 cols of one token s.
__global__ __launch_bounds__(256) void k_combine(
    const short* __restrict__ ob, const int* __restrict__ re_index,
    const float* __restrict__ topk, const float* __restrict__ shared_out,
    float* __restrict__ out)
{
  int s = blockIdx.x;
  int c0 = threadIdx.x * 8;
  const float* sh = shared_out + (size_t)s * H_ + c0;
  float4 s0 = *(const float4*)sh;
  float4 s1 = *(const float4*)(sh + 4);
  float r[8] = {s0.x, s0.y, s0.z, s0.w, s1.x, s1.y, s1.z, s1.w};
#pragma unroll
  for (int k = 0; k < K_; ++k) {
    int p = k * S_ + s;
    int idx = re_index[p];
    float wgt = topk[p];
    const short* row = ob + (size_t)idx * H_ + c0;
    short8 v = *(const short8*)row;
#pragma unroll
    for (int j = 0; j < 8; ++j) r[j] += wgt * bf2f(v[j]);
  }
  float* o = out + (size_t)s * H_ + c0;
  float4 o0, o1;
  o0.x = r[0]; o0.y = r[1]; o0.z = r[2]; o0.w = r[3];
  o1.x = r[4]; o1.y = r[5]; o1.z = r[6]; o1.w = r[7];
  *(float4*)o = o0;
  *(float4*)(o + 4) = o1;
}

extern "C" void kernel_launch(void* const* d_in, const int* in_sizes, int n_in,
                              void* d_out, int out_size, void* d_ws, size_t ws_size,
                              hipStream_t stream) {
  const float* hidden     = (const float*)d_in[0];
  const int*   tok        = (const int*)d_in[1];
  const int*   re_index   = (const int*)d_in[2];
  const float* topk       = (const float*)d_in[3];
  const float* shared_out = (const float*)d_in[4];
  const float* gw         = (const float*)d_in[5];
  const float* uw         = (const float*)d_in[6];
  const float* dw         = (const float*)d_in[7];
  float* out = (float*)d_out;

  char* ws = (char*)d_ws;
  short* xb = (short*)ws;                                   // [E][128][H] bf16, 83.9 MB
  short* hb = (short*)(ws + (size_t)E_ * MP_ * H_ * 2);     // [E][128][I] bf16, 7.9 MB
  short* ob = (short*)(ws + (size_t)E_ * MP_ * H_ * 2
                          + (size_t)E_ * MP_ * I_ * 2);     // [E*120][H] bf16, 78.6 MB

  hipLaunchKernelGGL(k_gather,  dim3(E_ * MP_), dim3(256), 0, stream, hidden, tok, xb);
  hipLaunchKernelGGL(k_gateup,  dim3(E_ * 3),   dim3(256), 0, stream, xb, gw, uw, hb);
  hipLaunchKernelGGL(k_down,    dim3(E_ * 16),  dim3(256), 0, stream, hb, dw, ob);
  hipLaunchKernelGGL(k_combine, dim3(S_),       dim3(256), 0, stream, ob, re_index, topk, shared_out, out);
}